// Round 5
// baseline (455.664 us; speedup 1.0000x reference)
//
#include <hip/hip_runtime.h>
#include <hip/hip_bf16.h>

#define D_IN 512
#define NEXP 32
#define HID 16
#define NT 34            // 544 cols / 16
#define KSTEPS 16        // 512 / 32
#define BM 128
#define BATCH 262144
#define GXL 129          // padded stride for gate-exchange LDS

typedef __attribute__((ext_vector_type(8))) short bfrag;   // 8 x bf16
typedef __attribute__((ext_vector_type(4))) float f32x4;

__device__ inline ushort f2bf(float f) {
  uint32_t u = __float_as_uint(f);
  u += 0x7fffu + ((u >> 16) & 1u);      // RNE, finite inputs
  return (ushort)(u >> 16);
}

// pack 8 fp32 -> 8 bf16 (RNE) with v_cvt_pk_bf16_f32
__device__ inline bfrag cvt8(const float4 a, const float4 b) {
  union { bfrag v; uint u[4]; } r;
  asm("v_cvt_pk_bf16_f32 %0, %1, %2" : "=v"(r.u[0]) : "v"(a.x), "v"(a.y));
  asm("v_cvt_pk_bf16_f32 %0, %1, %2" : "=v"(r.u[1]) : "v"(a.z), "v"(a.w));
  asm("v_cvt_pk_bf16_f32 %0, %1, %2" : "=v"(r.u[2]) : "v"(b.x), "v"(b.y));
  asm("v_cvt_pk_bf16_f32 %0, %1, %2" : "=v"(r.u[3]) : "v"(b.z), "v"(b.w));
  return r.v;
}

// tanh-form GELU, exp-based
__device__ inline float gelu_t(float v) {
  float t = 0.7978845608028654f * fmaf(0.044715f * v * v, v, v);
  t = fminf(fmaxf(t, -9.f), 9.f);
  float e = __expf(-2.f * t);
  float th = (1.f - e) * __builtin_amdgcn_rcpf(1.f + e);
  return 0.5f * v * (1.f + th);
}

__device__ inline void gload_lds16(const ushort* g, ushort* l) {
  __builtin_amdgcn_global_load_lds(
      (const __attribute__((address_space(1))) void*)g,
      (__attribute__((address_space(3))) void*)l, 16, 0, 0);
}

// ---- Pre-pack Wcat[512,544] into bf16 MFMA fragment order:
// P[ks][t][lane][j] = Wcat[k=ks*32+(l>>4)*8+j][n=t*16+(l&15)]
__global__ void prepack_kernel(const float* __restrict__ Wg,
                               const float* __restrict__ W1,
                               ushort* __restrict__ P) {
  int tid = blockIdx.x * 256 + threadIdx.x;
  const int total = KSTEPS * NT * 64;
  if (tid >= total) return;
  int l  = tid & 63;
  int t  = (tid >> 6) % NT;
  int ks = tid / (NT * 64);
  int n  = t * 16 + (l & 15);
  int kb = ks * 32 + (l >> 4) * 8;
  __align__(16) ushort v[8];
#pragma unroll
  for (int j = 0; j < 8; ++j) {
    int k = kb + j;
    float w;
    if (n < NEXP) {
      w = Wg[n * D_IN + k];
    } else {
      int e = (n - 32) >> 4, h = (n - 32) & 15;
      w = W1[(e * D_IN + k) * HID + h];
    }
    v[j] = f2bf(w);
  }
  *reinterpret_cast<int4*>(P + (size_t)tid * 8) = *reinterpret_cast<const int4*>(v);
}

// ---- Main fused kernel: BM=128 rows/block, 1024 thr = 16 waves (wm 0..3 x wn 0..3).
// Wave tile: 32 rows x 9 col-tiles (sets 0-8 / 9-17 / 17-25 / 25-33; 2 dupes keep
// the loop uniform). acc = 72 VGPR -> with launch_bounds(1024,4) total regs <=128
// -> 4 waves/SIMD (was 2: 248-reg class was the round-4 occupancy cap).
// acc = mfma(Wfrag, xfrag) -> C^T: lane&15 = batch row, (l>>4)*4+r = col-in-tile.
__global__ __launch_bounds__(1024, 4)
void moe_kernel(const float* __restrict__ x, const ushort* __restrict__ P,
                const float* __restrict__ b1, const float* __restrict__ W2,
                const float* __restrict__ b2, float* __restrict__ out) {
  __shared__ __align__(16) ushort Blds[2][NT * 512];   // 2 x 34 KiB, linear
  __shared__ float gall[NEXP * GXL];   // all 32 gate-exps per row, 16.5 KB
  __shared__ float pp[4][BM];          // per-wn partial sums
  __shared__ float sl[BM];             // softmax denom

  const int tid = threadIdx.x;
  const int l = tid & 63;
  const int wid = tid >> 6;
  const int wm = wid >> 2, wn = wid & 3;
  const int lane16 = l & 15, lg = l >> 4;
  const size_t rowBase = (size_t)blockIdx.x * BM;
  const int tbase = wn * 8 + (wn > 0);        // 0, 9, 17, 25

  f32x4 acc[2][9];
#pragma unroll
  for (int f = 0; f < 2; ++f)
#pragma unroll
    for (int t = 0; t < 9; ++t) acc[f][t] = (f32x4){0.f, 0.f, 0.f, 0.f};

  // x fragment: row = rowBase + wm*32 + f*16 + lane16, k = ks*32 + lg*8 + j
  const float* xp0 = x + (rowBase + wm * 32 + lane16) * D_IN + lg * 8;
  const float* xp1 = xp0 + 16 * D_IN;

  float4 abuf[4];   // single-buffered fp32 A; cvt to bf16 at kstep top frees it

  // ---- prologue: stage B(0), issue A(0)
#pragma unroll
  for (int tg = wid; tg < NT; tg += 16)
    gload_lds16(P + ((size_t)tg * 64 + l) * 8, &Blds[0][tg * 512]);
  abuf[0] = *reinterpret_cast<const float4*>(xp0);
  abuf[1] = *reinterpret_cast<const float4*>(xp0 + 4);
  abuf[2] = *reinterpret_cast<const float4*>(xp1);
  abuf[3] = *reinterpret_cast<const float4*>(xp1 + 4);
  asm volatile("s_waitcnt vmcnt(4)" ::: "memory");   // B(0) staged; A(0) flying
  __builtin_amdgcn_s_barrier();
  __builtin_amdgcn_sched_barrier(0);

#pragma unroll
  for (int ks = 0; ks < KSTEPS; ++ks) {
    const int cur = ks & 1, nxt = cur ^ 1;
    // consume A(ks): compiler auto-inserts the vmcnt wait for abuf
    const bfrag a0 = cvt8(abuf[0], abuf[1]);
    const bfrag a1 = cvt8(abuf[2], abuf[3]);
    if (ks < KSTEPS - 1) {
      // issue next B-stage (counted by the vmcnt(4) below), then next A
#pragma unroll
      for (int tg = wid; tg < NT; tg += 16)
        gload_lds16(P + ((size_t)((ks + 1) * NT + tg) * 64 + l) * 8,
                    &Blds[nxt][tg * 512]);
      abuf[0] = *reinterpret_cast<const float4*>(xp0 + (ks + 1) * 32);
      abuf[1] = *reinterpret_cast<const float4*>(xp0 + (ks + 1) * 32 + 4);
      abuf[2] = *reinterpret_cast<const float4*>(xp1 + (ks + 1) * 32);
      abuf[3] = *reinterpret_cast<const float4*>(xp1 + (ks + 1) * 32 + 4);
    }
#pragma unroll
    for (int t = 0; t < 9; ++t) {
      const bfrag b = *reinterpret_cast<const bfrag*>(
          &Blds[cur][(tbase + t) * 512 + l * 8]);
      acc[0][t] = __builtin_amdgcn_mfma_f32_16x16x32_bf16(b, a0, acc[0][t], 0, 0, 0);
      acc[1][t] = __builtin_amdgcn_mfma_f32_16x16x32_bf16(b, a1, acc[1][t], 0, 0, 0);
    }
    if (ks < KSTEPS - 1) {
      asm volatile("s_waitcnt vmcnt(4)" ::: "memory");  // B(k+1) in LDS; A(k+1) flying
      __builtin_amdgcn_s_barrier();
      __builtin_amdgcn_sched_barrier(0);
    }
  }

  // ---- epilogue. C^T: lane16 = row (within 16-group), lg*4+r = col-in-tile.
  const int row0 = wm * 32 + lane16;

  if (wn == 0) {
    // gating softmax from local tiles 0,1: expert e = t*16 + lg*4 + r
#pragma unroll
    for (int f = 0; f < 2; ++f) {
      const int row = row0 + f * 16;
      float mx = fmaxf(fmaxf(fmaxf(acc[f][0][0], acc[f][0][1]), fmaxf(acc[f][0][2], acc[f][0][3])),
                       fmaxf(fmaxf(acc[f][1][0], acc[f][1][1]), fmaxf(acc[f][1][2], acc[f][1][3])));
      mx = fmaxf(mx, __shfl_xor(mx, 16));
      mx = fmaxf(mx, __shfl_xor(mx, 32));
      float sum = 0.f;
#pragma unroll
      for (int t = 0; t < 2; ++t)
#pragma unroll
        for (int r = 0; r < 4; ++r) {
          float g = __expf(acc[f][t][r] - mx);
          sum += g;
          gall[(t * 16 + lg * 4 + r) * GXL + row] = g;
        }
      sum += __shfl_xor(sum, 16);
      sum += __shfl_xor(sum, 32);
      if (lg == 0) sl[row] = sum;
    }
  }
  __syncthreads();   // gates + denom visible to all waves

  // expert accumulation in place: e = eb + t, owned iff t >= tstart
  const int eb = wn * 8 - 1 - (wn == 0);              // -2, 7, 15, 23
  const int tstart = (wn == 0) ? 2 : ((wn == 1) ? 0 : 1);
  float pacc[2] = {0.f, 0.f};
#pragma unroll
  for (int t = 0; t < 9; ++t) {
    if (t >= tstart) {
      const int e = eb + t;
      const float4 b1v = *reinterpret_cast<const float4*>(b1 + e * HID + lg * 4);
      const float4 w2v = *reinterpret_cast<const float4*>(W2 + e * HID + lg * 4);
      const float b2v = b2[e];
#pragma unroll
      for (int f = 0; f < 2; ++f) {
        float p = gelu_t(acc[f][t][0] + b1v.x) * w2v.x;
        p = fmaf(gelu_t(acc[f][t][1] + b1v.y), w2v.y, p);
        p = fmaf(gelu_t(acc[f][t][2] + b1v.z), w2v.z, p);
        p = fmaf(gelu_t(acc[f][t][3] + b1v.w), w2v.w, p);
        p += __shfl_xor(p, 16);
        p += __shfl_xor(p, 32);             // o_e valid in all lanes
        pacc[f] = fmaf(p + b2v, gall[e * GXL + row0 + f * 16], pacc[f]);
      }
    }
  }
  if (lg == 0) {
    pp[wn][row0] = pacc[0];
    pp[wn][row0 + 16] = pacc[1];
  }
  __syncthreads();
  if (tid < BM) {
    float a = pp[0][tid] + pp[1][tid] + pp[2][tid] + pp[3][tid];
    out[rowBase + tid] = a / sl[tid];
  }
}

extern "C" void kernel_launch(void* const* d_in, const int* in_sizes, int n_in,
                              void* d_out, int out_size, void* d_ws, size_t ws_size,
                              hipStream_t stream) {
  const float* x  = (const float*)d_in[0];
  const float* Wg = (const float*)d_in[1];
  const float* W1 = (const float*)d_in[2];
  const float* b1 = (const float*)d_in[3];
  const float* W2 = (const float*)d_in[4];
  const float* b2 = (const float*)d_in[5];
  float* out = (float*)d_out;
  ushort* P = (ushort*)d_ws;   // 16*34*64*8*2 = 557,056 B

  hipLaunchKernelGGL(prepack_kernel, dim3((KSTEPS * NT * 64 + 255) / 256), dim3(256),
                     0, stream, Wg, W1, P);
  hipLaunchKernelGGL(moe_kernel, dim3(BATCH / BM), dim3(1024),
                     0, stream, x, P, b1, W2, b2, out);
}